// Round 3
// baseline (398.850 us; speedup 1.0000x reference)
//
#include <hip/hip_runtime.h>
#include <math.h>

// MultiBoxLoss (SSD) on MI355X.
// R9: kill k_select's 44us single-block-per-row stream (7% occupancy, 103KB
// LDS, 205 GB/s latency-bound). k_main now fuses per-exponent-bin (256 bins)
// {count | pred0-count (packed u32), float loss-sum} so above-boundary-bin
// negatives need NO key re-read. k_select runs full-GPU (16x64 blocks, 256
// thr): each block recomputes the pick from the merged 256-bin hist, scans
// only its own 16KB key slice for boundary-bin candidates (wave-aggregated
// append to a global per-row buffer), and the per-row LAST block (acq_rel
// row counter) radix-selects the remaining 23 bits (8+8+7) over the ~6K
// candidates in 4 small L2 passes, then the last row-finisher reduces the
// final outputs. Still exactly 2 dispatches; tie semantics unchanged.

#define MAXB 64
#define NSLOT 1024  // = (A/4096) * B = 16 * 64
#define NB1 256

struct Accum {
  float f_loc[NSLOT], f_clsp[NSLOT], f_perr[NSLOT], f_se0[NSLOT], f_se1[NSLOT];
  int i_pcor[NSLOT], i_pcnt[NSLOT];
  float f_clsn_row[MAXB];
  unsigned int i_ntot_row[MAXB], i_ncor_row[MAXB];
  unsigned int ccnt[MAXB], row_done[MAXB];
  unsigned int done;
};

__device__ __forceinline__ float iou_f(float4 g, float4 an) {
  float ax0 = an.x - an.z * 0.5f, ay0 = an.y - an.w * 0.5f;
  float ax1 = an.x + an.z * 0.5f, ay1 = an.y + an.w * 0.5f;
  float ltx = fmaxf(g.x, ax0), lty = fmaxf(g.y, ay0);
  float rbx = fminf(g.z, ax1), rby = fminf(g.w, ay1);
  float w = fmaxf(rbx - ltx, 0.f), h = fmaxf(rby - lty, 0.f);
  float inter = w * h;
  float area_g = (g.z - g.x) * (g.w - g.y);
  float area_a = (ax1 - ax0) * (ay1 - ay0);
  return inter / (area_g + area_a - inter);
}

__device__ __forceinline__ float sl1(float x) {
  float ax = fabsf(x);
  return ax < 1.f ? 0.5f * x * x : ax - 0.5f;
}

// keys + positive losses + fused 256-bin {count|ncor, sum} hist slices.
__global__ __launch_bounds__(256) void k_main(
    const float* __restrict__ loc_pred, const float* __restrict__ conf,
    const float* __restrict__ gt, const float* __restrict__ anchors,
    Accum* __restrict__ acc, unsigned int* __restrict__ g1c,
    float* __restrict__ g1s, unsigned int* __restrict__ keys, int A) {
  int b = blockIdx.y;
  int tid = threadIdx.x;
  int lane = tid & 63, wv = tid >> 6;
  __shared__ unsigned int hc[4][NB1];  // wave replicas: count | ncor<<16
  __shared__ float hs[4][NB1];         // wave replicas: float sum of k31
  __shared__ float smf[5][4];
  __shared__ int smi[2][4];
  for (int i = tid; i < 4 * NB1; i += 256) {
    ((unsigned int*)hc)[i] = 0u;
    ((float*)hs)[i] = 0.f;
  }
  __syncthreads();

  float4 g4 = reinterpret_cast<const float4*>(gt)[b];
  const float4* conf4 = reinterpret_cast<const float4*>(conf);
  const float4* anc4 = reinterpret_cast<const float4*>(anchors);
  const float4* loc4 = reinterpret_cast<const float4*>(loc_pred);
  int abase = blockIdx.x * 4096;
  long long cbase = ((long long)b * A + abase) >> 1;  // float4 units
  uint2* keys2 = reinterpret_cast<uint2*>(keys);

  float loc_s = 0.f, clsp = 0.f, perr = 0.f, se0 = 0.f, se1 = 0.f;
  int pcnt = 0, pcor = 0;

#pragma unroll
  for (int j = 0; j < 8; ++j) {
    float4 cc = conf4[cbase + tid + j * 256];
    int a0 = abase + 2 * (tid + j * 256);
    uint2 kv;
#pragma unroll
    for (int h = 0; h < 2; ++h) {
      int a = a0 + h;
      float c0 = h ? cc.z : cc.x;
      float c1 = h ? cc.w : cc.y;
      float4 an = anc4[a];
      float ov = iou_f(g4, an);
      unsigned int kk = 0u;
      if (ov <= 0.3f) {
        float m = fmaxf(c0, c1);
        float s = logf(expf(c0 - m) + expf(c1 - m));
        kk = __float_as_uint((m - c0) + s);
      }
      if (c1 > c0) kk |= 0x80000000u;
      if (h) kv.y = kk; else kv.x = kk;
      {
        unsigned int k31 = kk & 0x7FFFFFFFu;
        unsigned int bin = k31 >> 23;
        atomicAdd(&hc[wv][bin], 1u | ((((kk >> 31) ^ 1u) & 1u) << 16));
        if (k31) atomicAdd(&hs[wv][bin], __uint_as_float(k31));
      }
      if (ov >= 0.6f) {
        float4 lp = loc4[(long long)b * A + a];
        float gcx = (g4.x + g4.z) * 0.5f, gcy = (g4.y + g4.w) * 0.5f;
        float gw = g4.z - g4.x, gh = g4.w - g4.y;
        float t0 = (gcx - an.x) / (0.1f * an.z);
        float t1 = (gcy - an.y) / (0.1f * an.w);
        float t2 = logf(gw / an.z) / 0.2f;
        float t3 = logf(gh / an.w) / 0.2f;
        loc_s += sl1(lp.x - t0) + sl1(lp.y - t1) + sl1(lp.z - t2) +
                 sl1(lp.w - t3);
        float m = fmaxf(c0, c1);
        float s = logf(expf(c0 - m) + expf(c1 - m));
        clsp += (m - c1) + s;
        pcnt += 1;
        pcor += (c1 > c0) ? 1 : 0;
        float dcx = an.x + lp.x * 0.1f * an.z;
        float dcy = an.y + lp.y * 0.1f * an.w;
        float dw = an.z * expf(lp.z * 0.2f);
        float dh = an.w * expf(lp.w * 0.2f);
        float dx0 = dcx - dw * 0.5f, dy0 = dcy - dh * 0.5f;
        float ex = (g4.x - dx0) * 255.f, ey = (g4.y - dy0) * 255.f;
        perr += sqrtf(ex * ex + ey * ey);
        se0 += fabsf(g4.z - (dx0 + dw));
        se1 += fabsf(g4.w - (dy0 + dh));
      }
    }
    keys2[cbase + tid + j * 256] = kv;
  }

  // wave-reduce positive stats
  float fv[5] = {loc_s, clsp, perr, se0, se1};
  int iv[2] = {pcnt, pcor};
#pragma unroll
  for (int q = 0; q < 5; ++q) {
    float v = fv[q];
#pragma unroll
    for (int o = 32; o > 0; o >>= 1) v += __shfl_down(v, o, 64);
    if (lane == 0) smf[q][wv] = v;
  }
#pragma unroll
  for (int q = 0; q < 2; ++q) {
    int v = iv[q];
#pragma unroll
    for (int o = 32; o > 0; o >>= 1) v += __shfl_down(v, o, 64);
    if (lane == 0) smi[q][wv] = v;
  }
  __syncthreads();

  // flush hist slice (non-atomic: per-(row,block) region, no init needed)
  {
    int slot = b * gridDim.x + blockIdx.x;
    g1c[slot * NB1 + tid] = hc[0][tid] + hc[1][tid] + hc[2][tid] + hc[3][tid];
    g1s[slot * NB1 + tid] = hs[0][tid] + hs[1][tid] + hs[2][tid] + hs[3][tid];
  }

  if (tid == 0) {
    float L = 0, C = 0, P = 0, S0 = 0, S1 = 0;
    int PC = 0, COR = 0;
    for (int w2 = 0; w2 < 4; ++w2) {
      L += smf[0][w2]; C += smf[1][w2]; P += smf[2][w2];
      S0 += smf[3][w2]; S1 += smf[4][w2];
      PC += smi[0][w2]; COR += smi[1][w2];
    }
    int slot = b * gridDim.x + blockIdx.x;
    acc->f_loc[slot] = L;
    acc->f_clsp[slot] = C;
    acc->f_perr[slot] = P;
    acc->f_se0[slot] = S0;
    acc->f_se1[slot] = S1;
    acc->i_pcor[slot] = COR;
    acc->i_pcnt[slot] = PC;
    if (blockIdx.x == 0) {
      acc->ccnt[b] = 0u;
      acc->row_done[b] = 0u;
    }
    if (slot == 0) acc->done = 0u;
  }
}

// Block-wide pick over an LDS histogram of nbins (<=256) bins, one bin per
// thread. Finds bin where from-the-top cumulative crosses kr; returns
// (bin, residual rank) to all threads. 256-thread blocks.
__device__ uint2 pickB(const unsigned int* h, int nbins, int kr,
                       unsigned int* s_wsum, unsigned int* s_bin,
                       unsigned int* s_kr) {
  int tid = threadIdx.x, lane = tid & 63, wv = tid >> 6;
  unsigned int my = (tid < nbins) ? h[tid] : 0u;
  unsigned int v = my;
#pragma unroll
  for (int o = 1; o < 64; o <<= 1) {
    unsigned int tv = __shfl_down(v, o, 64);
    if (lane + o < 64) v += tv;
  }
  if (lane == 0) s_wsum[wv] = v;
  __syncthreads();
  unsigned int off = 0;
#pragma unroll
  for (int w2 = 0; w2 < 4; ++w2)
    if (w2 > wv) off += s_wsum[w2];
  unsigned int incl = v + off;
  unsigned int above = incl - my;
  if ((int)above < kr && kr <= (int)incl) {
    *s_bin = (unsigned int)tid;
    *s_kr = (unsigned int)(kr - (int)above);
  }
  __syncthreads();
  uint2 r;
  r.x = *s_bin;
  r.y = *s_kr;
  __syncthreads();
  return r;
}

__device__ __forceinline__ float bredf(float v, float* s4) {
#pragma unroll
  for (int o = 32; o > 0; o >>= 1) v += __shfl_down(v, o, 64);
  int lane = threadIdx.x & 63, wv = threadIdx.x >> 6;
  if (lane == 0) s4[wv] = v;
  __syncthreads();
  float r = s4[0] + s4[1] + s4[2] + s4[3];
  __syncthreads();
  return r;
}

__device__ __forceinline__ int bredi(int v, int* s4) {
#pragma unroll
  for (int o = 32; o > 0; o >>= 1) v += __shfl_down(v, o, 64);
  int lane = threadIdx.x & 63, wv = threadIdx.x >> 6;
  if (lane == 0) s4[wv] = v;
  __syncthreads();
  int r = s4[0] + s4[1] + s4[2] + s4[3];
  __syncthreads();
  return r;
}

// grid (spr, B), 256 threads. Every block: recompute pick from merged hist,
// scan own 16KB key slice for boundary-bin candidates. Last block per row:
// in-LDS radix select over candidates + row totals. Last row-finisher: out.
__global__ __launch_bounds__(256) void k_select(
    const unsigned int* __restrict__ keys, const unsigned int* __restrict__ g1c,
    const float* __restrict__ g1s, Accum* __restrict__ acc,
    unsigned int* __restrict__ cand, float* __restrict__ out, int A, int spr) {
  int b = blockIdx.y;
  int bx = blockIdx.x;
  int tid = threadIdx.x;
  int lane = tid & 63;
  __shared__ unsigned int hist[NB1];
  __shared__ unsigned int s_wsum[4];
  __shared__ unsigned int s_bin, s_kr;
  __shared__ int s_np[16];
  __shared__ unsigned int s_eq, s_last;
  __shared__ float s_f4[4];
  __shared__ int s_i4[4];

  // merge count|ncor slices (ncor kept in register; counts into LDS for pick)
  unsigned int cntm = 0, ncrm = 0;
  {
    const unsigned int* pc = g1c + (long long)b * spr * NB1 + tid;
    for (int s = 0; s < spr; ++s) {
      unsigned int p = pc[s * NB1];
      cntm += p & 0xFFFFu;
      ncrm += p >> 16;
    }
  }
  hist[tid] = cntm;
  if (tid < spr) s_np[tid] = acc->i_pcnt[b * spr + tid];
  if (tid == 0) s_eq = 0u;
  __syncthreads();

  int np = 0;
  for (int i = 0; i < spr; ++i) np += s_np[i];
  int k = 3 * np;
  if (k < 10) k = 10;
  if (k > A - 1) k = A - 1;

  uint2 p1 = pickB(hist, NB1, k, s_wsum, &s_bin, &s_kr);
  unsigned int tstar = p1.x;
  int r = (int)p1.y;

  // scan own slice: append boundary-bin keys to global per-row candidates
  {
    const uint4* k4 = reinterpret_cast<const uint4*>(keys);
    long long base4 = ((long long)b * A + (long long)bx * 4096) >> 2;
    unsigned int* crow = cand + (long long)b * A;
#pragma unroll
    for (int j = 0; j < 4; ++j) {
      uint4 v = k4[base4 + tid + j * 256];
      unsigned int ks[4] = {v.x, v.y, v.z, v.w};
#pragma unroll
      for (int e = 0; e < 4; ++e) {
        unsigned int key = ks[e];
        bool inb = ((key & 0x7FFFFFFFu) >> 23) == tstar;
        unsigned long long mb = __ballot(inb);
        if (mb) {
          int leader = __ffsll((unsigned long long)mb) - 1;
          unsigned int base = 0;
          if (lane == leader)
            base = atomicAdd(&acc->ccnt[b], (unsigned int)__popcll(mb));
          base = __shfl(base, leader, 64);
          if (inb)
            crow[base + __popcll(mb & ((1ull << lane) - 1ull))] = key;
        }
      }
    }
  }

  __threadfence();
  if (tid == 0) {
    unsigned int old = __hip_atomic_fetch_add(
        &acc->row_done[b], 1u, __ATOMIC_ACQ_REL, __HIP_MEMORY_SCOPE_AGENT);
    s_last = (old == (unsigned int)(gridDim.x - 1)) ? 1u : 0u;
  }
  __syncthreads();
  if (!s_last) return;
  __threadfence();

  // ---- row finisher ----
  unsigned int ccnt = __hip_atomic_load(&acc->ccnt[b], __ATOMIC_RELAXED,
                                        __HIP_MEMORY_SCOPE_AGENT);
  const unsigned int* crow = cand + (long long)b * A;

  // above-bin totals from fused per-bin sums
  float fs = 0.f;
  {
    const float* ps = g1s + (long long)b * spr * NB1 + tid;
    for (int s = 0; s < spr; ++s) fs += ps[s * NB1];
  }
  bool gtb = tid > (int)tstar;
  float a_fs = bredf(gtb ? fs : 0.f, s_f4);
  int a_cn = bredi(gtb ? (int)cntm : 0, s_i4);
  int a_nc = bredi(gtb ? (int)ncrm : 0, s_i4);

  // radix-select remaining 23 bits (8+8+7) among candidates
  unsigned int prefix = tstar;
  int pbits = 8;
#pragma unroll
  for (int lvl = 0; lvl < 3; ++lvl) {
    int nb = (lvl == 2) ? 7 : 8;
    int shN = 31 - pbits, sh2 = shN - nb;
    unsigned int msk = (1u << nb) - 1u;
    if (tid < (1 << nb)) hist[tid] = 0u;
    __syncthreads();
    for (unsigned int i = tid; i < ccnt; i += 256) {
      unsigned int k31 = crow[i] & 0x7FFFFFFFu;
      if ((k31 >> shN) == prefix) atomicAdd(&hist[(k31 >> sh2) & msk], 1u);
    }
    __syncthreads();
    uint2 pp = pickB(hist, 1 << nb, r, s_wsum, &s_bin, &s_kr);
    prefix = (prefix << nb) | pp.x;
    r = (int)pp.y;
    pbits += nb;
  }
  unsigned int thr = prefix;
  int need = r;

  // select among candidates
  float cls = 0.f;
  int ncnt = 0, ncor = 0;
  for (unsigned int i = tid; i < ccnt; i += 256) {
    unsigned int key = crow[i];
    unsigned int k31 = key & 0x7FFFFFFFu;
    bool s = false;
    if (k31 > thr) {
      s = true;
    } else if (k31 == thr) {
      unsigned int ord = atomicAdd(&s_eq, 1u);
      if ((int)ord < need) s = true;
    }
    if (s) {
      cls += __uint_as_float(k31);
      ncnt += 1;
      ncor += (int)((key >> 31) ^ 1u);
    }
  }
  float c_tot = bredf(cls, s_f4);
  int n_tot = bredi(ncnt, s_i4);
  int nc_tot = bredi(ncor, s_i4);

  if (tid == 0) {
    acc->f_clsn_row[b] = c_tot + a_fs;
    acc->i_ntot_row[b] = (unsigned int)(n_tot + a_cn);
    acc->i_ncor_row[b] = (unsigned int)(nc_tot + a_nc);
  }

  __threadfence();
  if (tid == 0) {
    unsigned int old = __hip_atomic_fetch_add(&acc->done, 1u, __ATOMIC_ACQ_REL,
                                              __HIP_MEMORY_SCOPE_AGENT);
    s_last = (old == (unsigned int)(gridDim.y - 1)) ? 1u : 0u;
  }
  __syncthreads();
  if (!s_last) return;
  __threadfence();

  // ---- final reduction (last row finisher) ----
  int nslot = spr * (int)gridDim.y;
  int B = (int)gridDim.y;
  float F[6] = {0, 0, 0, 0, 0, 0};
  int I[4] = {0, 0, 0, 0};
  for (int i = tid; i < nslot; i += 256) {
    F[0] += acc->f_loc[i];
    F[1] += acc->f_clsp[i];
    F[2] += acc->f_perr[i];
    F[3] += acc->f_se0[i];
    F[4] += acc->f_se1[i];
    I[0] += acc->i_pcor[i];
    I[1] += acc->i_pcnt[i];
  }
  for (int i = tid; i < B; i += 256) {
    F[5] += acc->f_clsn_row[i];
    I[2] += (int)acc->i_ntot_row[i];
    I[3] += (int)acc->i_ncor_row[i];
  }
  float T0 = bredf(F[0], s_f4);
  float T1 = bredf(F[1], s_f4);
  float T2 = bredf(F[2], s_f4);
  float T3 = bredf(F[3], s_f4);
  float T4 = bredf(F[4], s_f4);
  float T5 = bredf(F[5], s_f4);
  int P0 = bredi(I[0], s_i4);
  int P1 = bredi(I[1], s_i4);
  int P2 = bredi(I[2], s_i4);
  int P3 = bredi(I[3], s_i4);

  if (tid == 0) {
    float N = (float)P1;
    float Nf = fmaxf(N, 1.f);
    out[0] = T0 / (Nf * 4.f);
    float wsum = N + (float)P2 * (1.f / 3.f);
    out[1] = (T1 + T5 * (1.f / 3.f)) / wsum;
    out[2] = (float)P0 / fmaxf(N, 1.f);
    out[3] = (float)P3 / fmaxf((float)P2, 1.f);
    out[4] = T2 / Nf;
    out[5] = T3 / Nf * 255.f;
    out[6] = T4 / Nf * 255.f;
    out[7] = N;
  }
}

extern "C" void kernel_launch(void* const* d_in, const int* in_sizes, int n_in,
                              void* d_out, int out_size, void* d_ws,
                              size_t ws_size, hipStream_t stream) {
  (void)n_in; (void)out_size; (void)ws_size;
  const float* loc = (const float*)d_in[0];
  const float* conf = (const float*)d_in[1];
  const float* gt = (const float*)d_in[2];
  const float* anchors = (const float*)d_in[3];
  int B = in_sizes[2] / 4;  // 64
  int A = in_sizes[3] / 4;  // 65536
  float* out = (float*)d_out;

  int spr = A / 4096;  // 16 blocks per row

  char* w = (char*)d_ws;
  Accum* acc = (Accum*)w;
  size_t off = (sizeof(Accum) + 255) & ~(size_t)255;
  unsigned int* g1c = (unsigned int*)(w + off);
  off += (size_t)B * spr * NB1 * 4;
  float* g1s = (float*)(w + off);
  off += (size_t)B * spr * NB1 * 4;
  off = (off + 255) & ~(size_t)255;
  unsigned int* keys = (unsigned int*)(w + off);
  off += (size_t)B * A * 4;
  unsigned int* cand = (unsigned int*)(w + off);

  dim3 grid(spr, B);
  k_main<<<grid, 256, 0, stream>>>(loc, conf, gt, anchors, acc, g1c, g1s,
                                   keys, A);
  k_select<<<grid, 256, 0, stream>>>(keys, g1c, g1s, acc, cand, out, A, spr);
}

// Round 4
// 340.305 us; speedup vs baseline: 1.1720x; 1.1720x over previous
//
#include <hip/hip_runtime.h>
#include <math.h>

// MultiBoxLoss (SSD) on MI355X.
// R10: fix R9's 280us row-finisher (one 256-thr block serially streaming up
// to ~30K boundary-bin candidates from global; 8-bit first level too coarse).
// - k_main: fused hist now 2048 bins (bits[30:20]) -> boundary bin ~2-4K.
//   No float-sum/ncor side channels (scan re-reads its chunk anyway).
// - k_select: grid (A/16384, B) x 1024 thr. Every block merges the row hist
//   (uint2-coalesced) + picks; scans its own 64KB chunk: above-bin keys
//   accumulate in registers, in-bin keys ballot-append to a global row
//   buffer. Last block per row (acq_rel) radix-selects remaining 20 bits
//   (10+10) over ~2-4K candidates with 16 waves; last of 64 finishers
//   reduces the output. 31 bits = 11+10+10; tie semantics unchanged.
// Still exactly 2 dispatches.

#define MAXB 64
#define NSLOT 1024  // = (A/4096) * B = 16 * 64
#define NB 2048     // first-level bins, key bits [30:20]

struct Accum {
  float f_loc[NSLOT], f_clsp[NSLOT], f_perr[NSLOT], f_se0[NSLOT], f_se1[NSLOT];
  int i_pcor[NSLOT], i_pcnt[NSLOT];
  float f_clsn_row[MAXB];
  unsigned int i_ntot_row[MAXB], i_ncor_row[MAXB];
  unsigned int ccnt[MAXB], row_done[MAXB];
  unsigned int done;
};

__device__ __forceinline__ float iou_f(float4 g, float4 an) {
  float ax0 = an.x - an.z * 0.5f, ay0 = an.y - an.w * 0.5f;
  float ax1 = an.x + an.z * 0.5f, ay1 = an.y + an.w * 0.5f;
  float ltx = fmaxf(g.x, ax0), lty = fmaxf(g.y, ay0);
  float rbx = fminf(g.z, ax1), rby = fminf(g.w, ay1);
  float w = fmaxf(rbx - ltx, 0.f), h = fmaxf(rby - lty, 0.f);
  float inter = w * h;
  float area_g = (g.z - g.x) * (g.w - g.y);
  float area_a = (ax1 - ax0) * (ay1 - ay0);
  return inter / (area_g + area_a - inter);
}

__device__ __forceinline__ float sl1(float x) {
  float ax = fabsf(x);
  return ax < 1.f ? 0.5f * x * x : ax - 0.5f;
}

// keys + positive losses + fused 2048-bin count hist slices. grid (A/4096,B).
__global__ __launch_bounds__(256) void k_main(
    const float* __restrict__ loc_pred, const float* __restrict__ conf,
    const float* __restrict__ gt, const float* __restrict__ anchors,
    Accum* __restrict__ acc, unsigned int* __restrict__ g1c,
    unsigned int* __restrict__ keys, int A) {
  int b = blockIdx.y;
  int tid = threadIdx.x;
  int lane = tid & 63, wv = tid >> 6;
  __shared__ unsigned int hist[NB];  // single replica, 8 KB
  __shared__ float smf[5][4];
  __shared__ int smi[2][4];
  for (int i = tid; i < NB; i += 256) hist[i] = 0u;
  __syncthreads();

  float4 g4 = reinterpret_cast<const float4*>(gt)[b];
  const float4* conf4 = reinterpret_cast<const float4*>(conf);
  const float4* anc4 = reinterpret_cast<const float4*>(anchors);
  const float4* loc4 = reinterpret_cast<const float4*>(loc_pred);
  int abase = blockIdx.x * 4096;
  long long cbase = ((long long)b * A + abase) >> 1;  // float4 units
  uint2* keys2 = reinterpret_cast<uint2*>(keys);

  float loc_s = 0.f, clsp = 0.f, perr = 0.f, se0 = 0.f, se1 = 0.f;
  int pcnt = 0, pcor = 0;

#pragma unroll
  for (int j = 0; j < 8; ++j) {
    float4 cc = conf4[cbase + tid + j * 256];
    int a0 = abase + 2 * (tid + j * 256);
    uint2 kv;
#pragma unroll
    for (int h = 0; h < 2; ++h) {
      int a = a0 + h;
      float c0 = h ? cc.z : cc.x;
      float c1 = h ? cc.w : cc.y;
      float4 an = anc4[a];
      float ov = iou_f(g4, an);
      unsigned int kk = 0u;
      if (ov <= 0.3f) {
        float m = fmaxf(c0, c1);
        float s = logf(expf(c0 - m) + expf(c1 - m));
        kk = __float_as_uint((m - c0) + s);
      }
      if (c1 > c0) kk |= 0x80000000u;
      if (h) kv.y = kk; else kv.x = kk;
      atomicAdd(&hist[(kk & 0x7FFFFFFFu) >> 20], 1u);
      if (ov >= 0.6f) {
        float4 lp = loc4[(long long)b * A + a];
        float gcx = (g4.x + g4.z) * 0.5f, gcy = (g4.y + g4.w) * 0.5f;
        float gw = g4.z - g4.x, gh = g4.w - g4.y;
        float t0 = (gcx - an.x) / (0.1f * an.z);
        float t1 = (gcy - an.y) / (0.1f * an.w);
        float t2 = logf(gw / an.z) / 0.2f;
        float t3 = logf(gh / an.w) / 0.2f;
        loc_s += sl1(lp.x - t0) + sl1(lp.y - t1) + sl1(lp.z - t2) +
                 sl1(lp.w - t3);
        float m = fmaxf(c0, c1);
        float s = logf(expf(c0 - m) + expf(c1 - m));
        clsp += (m - c1) + s;
        pcnt += 1;
        pcor += (c1 > c0) ? 1 : 0;
        float dcx = an.x + lp.x * 0.1f * an.z;
        float dcy = an.y + lp.y * 0.1f * an.w;
        float dw = an.z * expf(lp.z * 0.2f);
        float dh = an.w * expf(lp.w * 0.2f);
        float dx0 = dcx - dw * 0.5f, dy0 = dcy - dh * 0.5f;
        float ex = (g4.x - dx0) * 255.f, ey = (g4.y - dy0) * 255.f;
        perr += sqrtf(ex * ex + ey * ey);
        se0 += fabsf(g4.z - (dx0 + dw));
        se1 += fabsf(g4.w - (dy0 + dh));
      }
    }
    keys2[cbase + tid + j * 256] = kv;
  }

  // wave-reduce positive stats
  float fv[5] = {loc_s, clsp, perr, se0, se1};
  int iv[2] = {pcnt, pcor};
#pragma unroll
  for (int q = 0; q < 5; ++q) {
    float v = fv[q];
#pragma unroll
    for (int o = 32; o > 0; o >>= 1) v += __shfl_down(v, o, 64);
    if (lane == 0) smf[q][wv] = v;
  }
#pragma unroll
  for (int q = 0; q < 2; ++q) {
    int v = iv[q];
#pragma unroll
    for (int o = 32; o > 0; o >>= 1) v += __shfl_down(v, o, 64);
    if (lane == 0) smi[q][wv] = v;
  }
  __syncthreads();

  // flush hist slice (non-atomic: per-(row,block) region, no init needed)
  {
    int slot = b * gridDim.x + blockIdx.x;
    unsigned int* dst = g1c + (long long)slot * NB;
    for (int i = tid; i < NB; i += 256) dst[i] = hist[i];
  }

  if (tid == 0) {
    float L = 0, C = 0, P = 0, S0 = 0, S1 = 0;
    int PC = 0, COR = 0;
    for (int w2 = 0; w2 < 4; ++w2) {
      L += smf[0][w2]; C += smf[1][w2]; P += smf[2][w2];
      S0 += smf[3][w2]; S1 += smf[4][w2];
      PC += smi[0][w2]; COR += smi[1][w2];
    }
    int slot = b * gridDim.x + blockIdx.x;
    acc->f_loc[slot] = L;
    acc->f_clsp[slot] = C;
    acc->f_perr[slot] = P;
    acc->f_se0[slot] = S0;
    acc->f_se1[slot] = S1;
    acc->i_pcor[slot] = COR;
    acc->i_pcnt[slot] = PC;
    if (blockIdx.x == 0) {
      acc->f_clsn_row[b] = 0.f;
      acc->i_ntot_row[b] = 0u;
      acc->i_ncor_row[b] = 0u;
      acc->ccnt[b] = 0u;
      acc->row_done[b] = 0u;
    }
    if (slot == 0) acc->done = 0u;
  }
}

// pick over per-thread register counts; thread t owns bins [t*PER,(t+1)*PER).
// 1024-thread blocks (16 waves). Finds bin where from-the-top cumulative
// crosses kr; returns (bin, residual rank) to all threads.
template <int PER>
__device__ uint2 pickR(const unsigned int* cnt, int kr,
                       unsigned int* s_wsum, volatile unsigned int* s_bin,
                       volatile unsigned int* s_kr) {
  const int tid = threadIdx.x, lane = tid & 63, wv = tid >> 6;
  unsigned int my = 0;
#pragma unroll
  for (int i = 0; i < PER; ++i) my += cnt[i];
  unsigned int v = my;
#pragma unroll
  for (int o = 1; o < 64; o <<= 1) {
    unsigned int tv = __shfl_down(v, o, 64);
    if (lane + o < 64) v += tv;
  }
  if (lane == 0) s_wsum[wv] = v;
  __syncthreads();
  unsigned int off = 0;
#pragma unroll
  for (int w2 = 0; w2 < 16; ++w2)
    if (w2 > wv) off += s_wsum[w2];
  unsigned int incl = v + off;
  unsigned int above = incl - my;
  if ((int)above < kr && kr <= (int)incl) {
    int kk = kr - (int)above;
#pragma unroll
    for (int i = PER - 1; i >= 0; --i) {
      int c = (int)cnt[i];
      if (kk <= c) {
        *s_bin = (unsigned int)(tid * PER + i);
        *s_kr = (unsigned int)kk;
        break;
      }
      kk -= c;
    }
  }
  __syncthreads();
  uint2 r;
  r.x = *s_bin;
  r.y = *s_kr;
  __syncthreads();
  return r;
}

__device__ __forceinline__ float bredf16(float v, float* s) {
#pragma unroll
  for (int o = 32; o > 0; o >>= 1) v += __shfl_down(v, o, 64);
  int lane = threadIdx.x & 63, wv = threadIdx.x >> 6;
  if (lane == 0) s[wv] = v;
  __syncthreads();
  float r = 0;
#pragma unroll
  for (int w = 0; w < 16; ++w) r += s[w];
  __syncthreads();
  return r;
}

__device__ __forceinline__ int bredi16(int v, int* s) {
#pragma unroll
  for (int o = 32; o > 0; o >>= 1) v += __shfl_down(v, o, 64);
  int lane = threadIdx.x & 63, wv = threadIdx.x >> 6;
  if (lane == 0) s[wv] = v;
  __syncthreads();
  int r = 0;
#pragma unroll
  for (int w = 0; w < 16; ++w) r += s[w];
  __syncthreads();
  return r;
}

// grid (A/16384, B) x 1024 thr. Merge hist + pick; scan own 64KB chunk
// (above-bin: register accumulate; in-bin: append to global row buffer).
// Last block per row: 10+10-bit radix over candidates. Last finisher: out.
__global__ __launch_bounds__(1024) void k_select(
    const unsigned int* __restrict__ keys, const unsigned int* __restrict__ g1c,
    Accum* __restrict__ acc, unsigned int* __restrict__ cand,
    float* __restrict__ out, int A, int spr) {
  int b = blockIdx.y;
  int bx = blockIdx.x;
  int tid = threadIdx.x;
  int lane = tid & 63;
  __shared__ unsigned int hist[1024];
  __shared__ unsigned int s_wsum[16];
  __shared__ volatile unsigned int s_bin, s_kr;
  __shared__ int s_np[16];
  __shared__ unsigned int s_eq, s_last;
  __shared__ float s_f[16];
  __shared__ int s_i[16];

  // phase A: merge per-slice hist counts (2 bins/thread, uint2-coalesced)
  unsigned int cnt2[2] = {0u, 0u};
  {
    const uint2* pc = reinterpret_cast<const uint2*>(
        g1c + (long long)b * spr * NB);
    for (int s = 0; s < spr; ++s) {
      uint2 p = pc[s * (NB / 2) + tid];
      cnt2[0] += p.x;
      cnt2[1] += p.y;
    }
  }
  if (tid < spr) s_np[tid] = acc->i_pcnt[b * spr + tid];
  if (tid == 0) s_eq = 0u;
  __syncthreads();

  int np = 0;
  for (int i = 0; i < spr; ++i) np += s_np[i];
  int k = 3 * np;
  if (k < 10) k = 10;
  if (k > A - 1) k = A - 1;

  uint2 p1 = pickR<2>(cnt2, k, s_wsum, &s_bin, &s_kr);
  unsigned int tstar = p1.x;
  int r = (int)p1.y;

  // phase B: scan own chunk (16 keys/thread)
  const uint4* k4 = reinterpret_cast<const uint4*>(keys);
  long long base4 = (((long long)b * A) >> 2) + (long long)bx * 4096;
  unsigned int* crow = cand + (long long)b * A;
  float cls = 0.f;
  int ncnt = 0, ncor = 0;
  uint4 v[4];
#pragma unroll
  for (int j = 0; j < 4; ++j) v[j] = k4[base4 + tid + j * 1024];
#pragma unroll
  for (int j = 0; j < 4; ++j) {
    unsigned int ks[4] = {v[j].x, v[j].y, v[j].z, v[j].w};
#pragma unroll
    for (int e = 0; e < 4; ++e) {
      unsigned int key = ks[e];
      unsigned int k31 = key & 0x7FFFFFFFu;
      unsigned int vp = k31 >> 20;
      if (vp > tstar) {
        cls += __uint_as_float(k31);
        ncnt += 1;
        ncor += (int)((key >> 31) ^ 1u);
      }
      bool inb = (vp == tstar);
      unsigned long long mb = __ballot(inb);
      if (mb) {
        int leader = __ffsll((unsigned long long)mb) - 1;
        unsigned int base = 0;
        if (lane == leader)
          base = atomicAdd(&acc->ccnt[b], (unsigned int)__popcll(mb));
        base = __shfl(base, leader, 64);
        if (inb) crow[base + __popcll(mb & ((1ull << lane) - 1ull))] = key;
      }
    }
  }

  // flush scan stats to row accumulators
  {
    float C = bredf16(cls, s_f);
    int NC = bredi16(ncnt, s_i);
    int CR = bredi16(ncor, s_i);
    if (tid == 0) {
      atomicAdd(&acc->f_clsn_row[b], C);
      atomicAdd(&acc->i_ntot_row[b], (unsigned int)NC);
      atomicAdd(&acc->i_ncor_row[b], (unsigned int)CR);
    }
  }

  __threadfence();
  if (tid == 0) {
    unsigned int old = __hip_atomic_fetch_add(
        &acc->row_done[b], 1u, __ATOMIC_ACQ_REL, __HIP_MEMORY_SCOPE_AGENT);
    s_last = (old == (unsigned int)(gridDim.x - 1)) ? 1u : 0u;
  }
  __syncthreads();
  if (!s_last) return;
  __threadfence();

  // ---- row finisher: radix-select remaining 20 bits over candidates ----
  unsigned int ccnt = __hip_atomic_load(&acc->ccnt[b], __ATOMIC_RELAXED,
                                        __HIP_MEMORY_SCOPE_AGENT);
  // level 2: bits [19:10]
  hist[tid] = 0u;
  __syncthreads();
  for (unsigned int i = tid; i < ccnt; i += 1024)
    atomicAdd(&hist[((crow[i] & 0x7FFFFFFFu) >> 10) & 0x3FFu], 1u);
  __syncthreads();
  unsigned int c1 = hist[tid];
  uint2 p2 = pickR<1>(&c1, r, s_wsum, &s_bin, &s_kr);
  unsigned int pref21 = (tstar << 10) | p2.x;
  r = (int)p2.y;

  // level 3: bits [9:0]
  hist[tid] = 0u;
  __syncthreads();
  for (unsigned int i = tid; i < ccnt; i += 1024) {
    unsigned int k31 = crow[i] & 0x7FFFFFFFu;
    if ((k31 >> 10) == pref21) atomicAdd(&hist[k31 & 0x3FFu], 1u);
  }
  __syncthreads();
  unsigned int c2 = hist[tid];
  uint2 p3 = pickR<1>(&c2, r, s_wsum, &s_bin, &s_kr);
  unsigned int thr = (pref21 << 10) | p3.x;
  int need = (int)p3.y;

  // select among candidates
  float cls2 = 0.f;
  int ncnt2 = 0, ncor2 = 0;
  for (unsigned int i = tid; i < ccnt; i += 1024) {
    unsigned int key = crow[i];
    unsigned int k31 = key & 0x7FFFFFFFu;
    bool s = false;
    if (k31 > thr) {
      s = true;
    } else if (k31 == thr) {
      unsigned int ord = atomicAdd(&s_eq, 1u);
      if ((int)ord < need) s = true;
    }
    if (s) {
      cls2 += __uint_as_float(k31);
      ncnt2 += 1;
      ncor2 += (int)((key >> 31) ^ 1u);
    }
  }
  {
    float C = bredf16(cls2, s_f);
    int NC = bredi16(ncnt2, s_i);
    int CR = bredi16(ncor2, s_i);
    if (tid == 0) {
      atomicAdd(&acc->f_clsn_row[b], C);
      atomicAdd(&acc->i_ntot_row[b], (unsigned int)NC);
      atomicAdd(&acc->i_ncor_row[b], (unsigned int)CR);
    }
  }

  __threadfence();
  if (tid == 0) {
    unsigned int old = __hip_atomic_fetch_add(&acc->done, 1u, __ATOMIC_ACQ_REL,
                                              __HIP_MEMORY_SCOPE_AGENT);
    s_last = (old == (unsigned int)(gridDim.y - 1)) ? 1u : 0u;
  }
  __syncthreads();
  if (!s_last) return;
  __threadfence();

  // ---- final reduction (last row finisher) ----
  int B = (int)gridDim.y;
  int nslot = spr * B;
  float F0 = 0, F1 = 0, F2 = 0, F3 = 0, F4 = 0, F5 = 0;
  int I0 = 0, I1 = 0, I2 = 0, I3 = 0;
  for (int i = tid; i < nslot; i += 1024) {
    F0 += acc->f_loc[i];
    F1 += acc->f_clsp[i];
    F2 += acc->f_perr[i];
    F3 += acc->f_se0[i];
    F4 += acc->f_se1[i];
    I0 += acc->i_pcor[i];
    I1 += acc->i_pcnt[i];
  }
  for (int i = tid; i < B; i += 1024) {
    F5 += acc->f_clsn_row[i];
    I2 += (int)acc->i_ntot_row[i];
    I3 += (int)acc->i_ncor_row[i];
  }
  float T0 = bredf16(F0, s_f);
  float T1 = bredf16(F1, s_f);
  float T2 = bredf16(F2, s_f);
  float T3 = bredf16(F3, s_f);
  float T4 = bredf16(F4, s_f);
  float T5 = bredf16(F5, s_f);
  int P0 = bredi16(I0, s_i);
  int P1 = bredi16(I1, s_i);
  int P2 = bredi16(I2, s_i);
  int P3 = bredi16(I3, s_i);

  if (tid == 0) {
    float N = (float)P1;
    float Nf = fmaxf(N, 1.f);
    out[0] = T0 / (Nf * 4.f);
    float wsum = N + (float)P2 * (1.f / 3.f);
    out[1] = (T1 + T5 * (1.f / 3.f)) / wsum;
    out[2] = (float)P0 / fmaxf(N, 1.f);
    out[3] = (float)P3 / fmaxf((float)P2, 1.f);
    out[4] = T2 / Nf;
    out[5] = T3 / Nf * 255.f;
    out[6] = T4 / Nf * 255.f;
    out[7] = N;
  }
}

extern "C" void kernel_launch(void* const* d_in, const int* in_sizes, int n_in,
                              void* d_out, int out_size, void* d_ws,
                              size_t ws_size, hipStream_t stream) {
  (void)n_in; (void)out_size; (void)ws_size;
  const float* loc = (const float*)d_in[0];
  const float* conf = (const float*)d_in[1];
  const float* gt = (const float*)d_in[2];
  const float* anchors = (const float*)d_in[3];
  int B = in_sizes[2] / 4;  // 64
  int A = in_sizes[3] / 4;  // 65536
  float* out = (float*)d_out;

  int spr = A / 4096;  // 16 k_main blocks per row

  char* w = (char*)d_ws;
  Accum* acc = (Accum*)w;
  size_t off = (sizeof(Accum) + 255) & ~(size_t)255;
  unsigned int* g1c = (unsigned int*)(w + off);
  off += (size_t)B * spr * NB * 4;
  off = (off + 255) & ~(size_t)255;
  unsigned int* keys = (unsigned int*)(w + off);
  off += (size_t)B * A * 4;
  unsigned int* cand = (unsigned int*)(w + off);

  dim3 gmain(spr, B);
  dim3 gsel(A / 16384, B);
  k_main<<<gmain, 256, 0, stream>>>(loc, conf, gt, anchors, acc, g1c, keys, A);
  k_select<<<gsel, 1024, 0, stream>>>(keys, g1c, acc, cand, out, A, spr);
}

// Round 5
// 172.559 us; speedup vs baseline: 2.3114x; 1.9721x over previous
//
#include <hip/hip_runtime.h>
#include <math.h>

// MultiBoxLoss (SSD) on MI355X.
// R11: R9/R10's regression was agent-scope fences + acq_rel atomics + global
// cand appends executed per scan block (~500+ L2 writeback/invalidates).
// Back to R8's fence-light shape with the fixes R8 lacked:
// - k_main: 4 wave-private 2048-bin hist replicas (bits[30:20]); one-expf
//   softplus (bit-identical: logf(1+expf(-|d|)) since expf(0)==1).
// - k_select: ONE 1024-thr block per row (64 blocks, no cross-block scan
//   gating). Merge 16 hist slices (L3-hot), pick 11 bits, stream own row's
//   256KB once: above-bin keys -> register accumulate; in-bin (~2-4K) ->
//   ballot-aggregated LDS cand append (leader-only atomic). Finish 20 bits
//   in-LDS. Plain-store row results; single done-counter gate (64 fence
//   executions total, like R8) for the fused final reduction.
// Exactly 2 dispatches; tie semantics unchanged.

#define MAXB 64
#define NSLOT 1024  // = (A/4096) * B = 16 * 64
#define NB 2048     // first-level bins, key bits [30:20]
#define CAP 16384   // LDS candidate buffer (64 KB)

struct Accum {
  float f_loc[NSLOT], f_clsp[NSLOT], f_perr[NSLOT], f_se0[NSLOT], f_se1[NSLOT];
  int i_pcor[NSLOT], i_pcnt[NSLOT];
  float f_clsn_row[MAXB];
  unsigned int i_ntot_row[MAXB], i_ncor_row[MAXB];
  unsigned int done;
};

__device__ __forceinline__ float iou_f(float4 g, float4 an) {
  float ax0 = an.x - an.z * 0.5f, ay0 = an.y - an.w * 0.5f;
  float ax1 = an.x + an.z * 0.5f, ay1 = an.y + an.w * 0.5f;
  float ltx = fmaxf(g.x, ax0), lty = fmaxf(g.y, ay0);
  float rbx = fminf(g.z, ax1), rby = fminf(g.w, ay1);
  float w = fmaxf(rbx - ltx, 0.f), h = fmaxf(rby - lty, 0.f);
  float inter = w * h;
  float area_g = (g.z - g.x) * (g.w - g.y);
  float area_a = (ax1 - ax0) * (ay1 - ay0);
  return inter / (area_g + area_a - inter);
}

__device__ __forceinline__ float sl1(float x) {
  float ax = fabsf(x);
  return ax < 1.f ? 0.5f * x * x : ax - 0.5f;
}

// keys + positive losses + fused 2048-bin count hist slices. grid (A/4096,B).
__global__ __launch_bounds__(256) void k_main(
    const float* __restrict__ loc_pred, const float* __restrict__ conf,
    const float* __restrict__ gt, const float* __restrict__ anchors,
    Accum* __restrict__ acc, unsigned int* __restrict__ g1c,
    unsigned int* __restrict__ keys, int A) {
  int b = blockIdx.y;
  int tid = threadIdx.x;
  int lane = tid & 63, wv = tid >> 6;
  __shared__ unsigned int hist[4][NB];  // wave-private replicas, 32 KB
  __shared__ float smf[5][4];
  __shared__ int smi[2][4];
  for (int i = tid; i < 4 * NB; i += 256) ((unsigned int*)hist)[i] = 0u;
  __syncthreads();

  float4 g4 = reinterpret_cast<const float4*>(gt)[b];
  const float4* conf4 = reinterpret_cast<const float4*>(conf);
  const float4* anc4 = reinterpret_cast<const float4*>(anchors);
  const float4* loc4 = reinterpret_cast<const float4*>(loc_pred);
  int abase = blockIdx.x * 4096;
  long long cbase = ((long long)b * A + abase) >> 1;  // float4 units
  uint2* keys2 = reinterpret_cast<uint2*>(keys);

  float loc_s = 0.f, clsp = 0.f, perr = 0.f, se0 = 0.f, se1 = 0.f;
  int pcnt = 0, pcor = 0;

#pragma unroll
  for (int j = 0; j < 8; ++j) {
    float4 cc = conf4[cbase + tid + j * 256];
    int a0 = abase + 2 * (tid + j * 256);
    uint2 kv;
#pragma unroll
    for (int h = 0; h < 2; ++h) {
      int a = a0 + h;
      float c0 = h ? cc.z : cc.x;
      float c1 = h ? cc.w : cc.y;
      float4 an = anc4[a];
      float ov = iou_f(g4, an);
      // softplus: logf(1+expf(-|d|)) is bit-identical to the two-expf form
      // (expf(0.f)==1.f exactly); saves one v_exp chain per key.
      float s = logf(1.0f + expf(-fabsf(c1 - c0)));
      float m = fmaxf(c0, c1);
      unsigned int kk = 0u;
      if (ov <= 0.3f) kk = __float_as_uint((m - c0) + s);
      if (c1 > c0) kk |= 0x80000000u;
      if (h) kv.y = kk; else kv.x = kk;
      atomicAdd(&hist[wv][(kk & 0x7FFFFFFFu) >> 20], 1u);
      if (ov >= 0.6f) {
        float4 lp = loc4[(long long)b * A + a];
        float gcx = (g4.x + g4.z) * 0.5f, gcy = (g4.y + g4.w) * 0.5f;
        float gw = g4.z - g4.x, gh = g4.w - g4.y;
        float t0 = (gcx - an.x) / (0.1f * an.z);
        float t1 = (gcy - an.y) / (0.1f * an.w);
        float t2 = logf(gw / an.z) / 0.2f;
        float t3 = logf(gh / an.w) / 0.2f;
        loc_s += sl1(lp.x - t0) + sl1(lp.y - t1) + sl1(lp.z - t2) +
                 sl1(lp.w - t3);
        clsp += (m - c1) + s;
        pcnt += 1;
        pcor += (c1 > c0) ? 1 : 0;
        float dcx = an.x + lp.x * 0.1f * an.z;
        float dcy = an.y + lp.y * 0.1f * an.w;
        float dw = an.z * expf(lp.z * 0.2f);
        float dh = an.w * expf(lp.w * 0.2f);
        float dx0 = dcx - dw * 0.5f, dy0 = dcy - dh * 0.5f;
        float ex = (g4.x - dx0) * 255.f, ey = (g4.y - dy0) * 255.f;
        perr += sqrtf(ex * ex + ey * ey);
        se0 += fabsf(g4.z - (dx0 + dw));
        se1 += fabsf(g4.w - (dy0 + dh));
      }
    }
    keys2[cbase + tid + j * 256] = kv;
  }

  // wave-reduce positive stats
  float fv[5] = {loc_s, clsp, perr, se0, se1};
  int iv[2] = {pcnt, pcor};
#pragma unroll
  for (int q = 0; q < 5; ++q) {
    float v = fv[q];
#pragma unroll
    for (int o = 32; o > 0; o >>= 1) v += __shfl_down(v, o, 64);
    if (lane == 0) smf[q][wv] = v;
  }
#pragma unroll
  for (int q = 0; q < 2; ++q) {
    int v = iv[q];
#pragma unroll
    for (int o = 32; o > 0; o >>= 1) v += __shfl_down(v, o, 64);
    if (lane == 0) smi[q][wv] = v;
  }
  __syncthreads();

  // flush hist slice (non-atomic: per-(row,block) region, no init needed)
  {
    int slot = b * gridDim.x + blockIdx.x;
    unsigned int* dst = g1c + (long long)slot * NB;
    for (int i = tid; i < NB; i += 256)
      dst[i] = hist[0][i] + hist[1][i] + hist[2][i] + hist[3][i];
  }

  if (tid == 0) {
    float L = 0, C = 0, P = 0, S0 = 0, S1 = 0;
    int PC = 0, COR = 0;
    for (int w2 = 0; w2 < 4; ++w2) {
      L += smf[0][w2]; C += smf[1][w2]; P += smf[2][w2];
      S0 += smf[3][w2]; S1 += smf[4][w2];
      PC += smi[0][w2]; COR += smi[1][w2];
    }
    int slot = b * gridDim.x + blockIdx.x;
    acc->f_loc[slot] = L;
    acc->f_clsp[slot] = C;
    acc->f_perr[slot] = P;
    acc->f_se0[slot] = S0;
    acc->f_se1[slot] = S1;
    acc->i_pcor[slot] = COR;
    acc->i_pcnt[slot] = PC;
    if (slot == 0) acc->done = 0u;
  }
}

// pick over per-thread register counts; thread t owns bins [t*PER,(t+1)*PER).
// 1024-thread blocks (16 waves). Finds bin where from-the-top cumulative
// crosses kr; returns (bin, residual rank) to all threads.
template <int PER>
__device__ uint2 pickR(const unsigned int* cnt, int kr, unsigned int* s_wsum,
                       volatile unsigned int* s_bin,
                       volatile unsigned int* s_kr) {
  const int tid = threadIdx.x, lane = tid & 63, wv = tid >> 6;
  unsigned int my = 0;
#pragma unroll
  for (int i = 0; i < PER; ++i) my += cnt[i];
  unsigned int v = my;
#pragma unroll
  for (int o = 1; o < 64; o <<= 1) {
    unsigned int tv = __shfl_down(v, o, 64);
    if (lane + o < 64) v += tv;
  }
  if (lane == 0) s_wsum[wv] = v;
  __syncthreads();
  unsigned int off = 0;
#pragma unroll
  for (int w2 = 0; w2 < 16; ++w2)
    if (w2 > wv) off += s_wsum[w2];
  unsigned int incl = v + off;
  unsigned int above = incl - my;
  if ((int)above < kr && kr <= (int)incl) {
    int kk = kr - (int)above;
#pragma unroll
    for (int i = PER - 1; i >= 0; --i) {
      int c = (int)cnt[i];
      if (kk <= c) {
        *s_bin = (unsigned int)(tid * PER + i);
        *s_kr = (unsigned int)kk;
        break;
      }
      kk -= c;
    }
  }
  __syncthreads();
  uint2 r;
  r.x = *s_bin;
  r.y = *s_kr;
  __syncthreads();
  return r;
}

__device__ __forceinline__ float bredf16(float v, float* s) {
#pragma unroll
  for (int o = 32; o > 0; o >>= 1) v += __shfl_down(v, o, 64);
  int lane = threadIdx.x & 63, wv = threadIdx.x >> 6;
  if (lane == 0) s[wv] = v;
  __syncthreads();
  float r = 0;
#pragma unroll
  for (int w = 0; w < 16; ++w) r += s[w];
  __syncthreads();
  return r;
}

__device__ __forceinline__ int bredi16(int v, int* s) {
#pragma unroll
  for (int o = 32; o > 0; o >>= 1) v += __shfl_down(v, o, 64);
  int lane = threadIdx.x & 63, wv = threadIdx.x >> 6;
  if (lane == 0) s[wv] = v;
  __syncthreads();
  int r = 0;
#pragma unroll
  for (int w = 0; w < 16; ++w) r += s[w];
  __syncthreads();
  return r;
}

// One 1024-thr block per row. Merge hist + pick; stream own row once
// (above-bin: registers; in-bin: LDS cand via ballot append); finish 20 bits
// in LDS; plain-store row results. Last row block: final output reduction.
__global__ __launch_bounds__(1024) void k_select(
    const unsigned int* __restrict__ keys, const unsigned int* __restrict__ g1c,
    Accum* __restrict__ acc, float* __restrict__ out, int A, int spr) {
  int b = blockIdx.x;
  int tid = threadIdx.x;
  int lane = tid & 63;
  __shared__ unsigned int cand[CAP];   // 64 KB
  __shared__ unsigned int hist2[1024]; // 4 KB, reused per level
  __shared__ unsigned int s_wsum[16];
  __shared__ volatile unsigned int s_bin, s_kr;
  __shared__ unsigned int s_cb;
  __shared__ int s_np[16];
  __shared__ unsigned int s_ccnt, s_eq, s_last;
  __shared__ float s_f[16];
  __shared__ int s_i[16];

  // phase A: merge the row's spr hist slices (2 bins/thread, uint2 loads)
  unsigned int cnt2[2] = {0u, 0u};
  {
    const uint2* pc =
        reinterpret_cast<const uint2*>(g1c + (long long)b * spr * NB);
    for (int s = 0; s < spr; ++s) {
      uint2 p = pc[s * (NB / 2) + tid];
      cnt2[0] += p.x;
      cnt2[1] += p.y;
    }
  }
  if (tid < spr) s_np[tid] = acc->i_pcnt[b * spr + tid];
  if (tid == 0) {
    s_ccnt = 0u;
    s_eq = 0u;
  }
  __syncthreads();

  int np = 0;
  for (int i = 0; i < spr; ++i) np += s_np[i];
  int k = 3 * np;
  if (k < 10) k = 10;
  if (k > A - 1) k = A - 1;

  uint2 p1 = pickR<2>(cnt2, k, s_wsum, &s_bin, &s_kr);
  unsigned int prefix = p1.x;
  int r = (int)p1.y;
  int pbits = 11;
  if (tid == (int)(p1.x >> 1)) s_cb = cnt2[p1.x & 1];
  __syncthreads();
  unsigned int cbin = s_cb;

  const uint4* k4 = reinterpret_cast<const uint4*>(keys);
  long long base4 = ((long long)b * A) >> 2;

  // rare fallback: streaming 10-bit refines until the bin fits LDS
  while (cbin > CAP && pbits < 31) {
    int nb = 31 - pbits;
    if (nb > 10) nb = 10;
    int shN = 31 - pbits, sh2 = shN - nb;
    unsigned int msk = (1u << nb) - 1u;
    hist2[tid] = 0u;
    __syncthreads();
    for (int j = 0; j < spr; ++j) {
      uint4 v = k4[base4 + tid + j * 1024];
      unsigned int ks[4] = {v.x, v.y, v.z, v.w};
#pragma unroll
      for (int e = 0; e < 4; ++e) {
        unsigned int k31 = ks[e] & 0x7FFFFFFFu;
        if ((k31 >> shN) == prefix) atomicAdd(&hist2[(k31 >> sh2) & msk], 1u);
      }
    }
    __syncthreads();
    unsigned int c = (tid < (1 << nb)) ? hist2[tid] : 0u;
    uint2 pp = pickR<1>(&c, r, s_wsum, &s_bin, &s_kr);
    prefix = (prefix << nb) | pp.x;
    r = (int)pp.y;
    pbits += nb;
    if (tid == (int)pp.x) s_cb = c;
    __syncthreads();
    cbin = s_cb;
  }

  float cls = 0.f;
  int ncnt = 0, ncor = 0;

  if (pbits < 31) {
    int shift = 31 - pbits;
    // ONE streaming pass over the row's keys
    for (int half = 0; half < 2; ++half) {
      uint4 v[8];
#pragma unroll
      for (int j = 0; j < 8; ++j)
        v[j] = k4[base4 + tid + (half * 8 + j) * 1024];
#pragma unroll
      for (int j = 0; j < 8; ++j) {
        unsigned int ks[4] = {v[j].x, v[j].y, v[j].z, v[j].w};
#pragma unroll
        for (int e = 0; e < 4; ++e) {
          unsigned int key = ks[e];
          unsigned int k31 = key & 0x7FFFFFFFu;
          unsigned int vp = k31 >> shift;
          if (vp > prefix) {
            cls += __uint_as_float(k31);
            ncnt += 1;
            ncor += (int)((key >> 31) ^ 1u);
          }
          bool inb = (vp == prefix);
          unsigned long long mb = __ballot(inb);
          if (mb) {
            int leader = __ffsll((unsigned long long)mb) - 1;
            unsigned int base = 0;
            if (lane == leader)
              base = atomicAdd(&s_ccnt, (unsigned int)__popcll(mb));
            base = __shfl(base, leader, 64);
            if (inb) cand[base + __popcll(mb & ((1ull << lane) - 1ull))] = key;
          }
        }
      }
    }
    __syncthreads();
    unsigned int ccnt = s_ccnt;

    // in-LDS radix over the remaining bits among candidates
    while (pbits < 31) {
      int nb = 31 - pbits;
      if (nb > 10) nb = 10;
      int shN = 31 - pbits, sh2 = shN - nb;
      unsigned int msk = (1u << nb) - 1u;
      hist2[tid] = 0u;
      __syncthreads();
      for (unsigned int i = tid; i < ccnt; i += 1024) {
        unsigned int k31 = cand[i] & 0x7FFFFFFFu;
        if ((k31 >> shN) == prefix) atomicAdd(&hist2[(k31 >> sh2) & msk], 1u);
      }
      __syncthreads();
      unsigned int c = (tid < (1 << nb)) ? hist2[tid] : 0u;
      uint2 pp = pickR<1>(&c, r, s_wsum, &s_bin, &s_kr);
      prefix = (prefix << nb) | pp.x;
      r = (int)pp.y;
      pbits += nb;
    }
    unsigned int thr = prefix;
    int need = r;
    for (unsigned int i = tid; i < ccnt; i += 1024) {
      unsigned int key = cand[i];
      unsigned int k31 = key & 0x7FFFFFFFu;
      bool s = false;
      if (k31 > thr) {
        s = true;
      } else if (k31 == thr) {
        unsigned int ord = atomicAdd(&s_eq, 1u);
        if ((int)ord < need) s = true;
      }
      if (s) {
        cls += __uint_as_float(k31);
        ncnt += 1;
        ncor += (int)((key >> 31) ^ 1u);
      }
    }
  } else {
    // degenerate: prefix is the full 31-bit threshold; stream-select ties
    unsigned int thr = prefix;
    int need = r;
    for (int j = 0; j < spr; ++j) {
      uint4 v = k4[base4 + tid + j * 1024];
      unsigned int ks[4] = {v.x, v.y, v.z, v.w};
#pragma unroll
      for (int e = 0; e < 4; ++e) {
        unsigned int key = ks[e];
        unsigned int k31 = key & 0x7FFFFFFFu;
        bool s = false;
        if (k31 > thr) {
          s = true;
        } else if (k31 == thr) {
          unsigned int ord = atomicAdd(&s_eq, 1u);
          if ((int)ord < need) s = true;
        }
        if (s) {
          cls += __uint_as_float(k31);
          ncnt += 1;
          ncor += (int)((key >> 31) ^ 1u);
        }
      }
    }
  }

  // block-reduce negative stats -> plain stores (single writer per row)
  {
    float C = bredf16(cls, s_f);
    int NC = bredi16(ncnt, s_i);
    int CR = bredi16(ncor, s_i);
    if (tid == 0) {
      acc->f_clsn_row[b] = C;
      acc->i_ntot_row[b] = (unsigned int)NC;
      acc->i_ncor_row[b] = (unsigned int)CR;
    }
  }

  // last-row-done final reduction (64 fence executions total)
  __threadfence();
  if (tid == 0) {
    unsigned int old = __hip_atomic_fetch_add(&acc->done, 1u, __ATOMIC_ACQ_REL,
                                              __HIP_MEMORY_SCOPE_AGENT);
    s_last = (old == (unsigned int)(gridDim.x - 1)) ? 1u : 0u;
  }
  __syncthreads();
  if (!s_last) return;
  __threadfence();

  int B = (int)gridDim.x;
  int nslot = spr * B;
  float F0 = 0, F1 = 0, F2 = 0, F3 = 0, F4 = 0, F5 = 0;
  int I0 = 0, I1 = 0, I2 = 0, I3 = 0;
  for (int i = tid; i < nslot; i += 1024) {
    F0 += acc->f_loc[i];
    F1 += acc->f_clsp[i];
    F2 += acc->f_perr[i];
    F3 += acc->f_se0[i];
    F4 += acc->f_se1[i];
    I0 += acc->i_pcor[i];
    I1 += acc->i_pcnt[i];
  }
  for (int i = tid; i < B; i += 1024) {
    F5 += acc->f_clsn_row[i];
    I2 += (int)acc->i_ntot_row[i];
    I3 += (int)acc->i_ncor_row[i];
  }
  float T0 = bredf16(F0, s_f);
  float T1 = bredf16(F1, s_f);
  float T2 = bredf16(F2, s_f);
  float T3 = bredf16(F3, s_f);
  float T4 = bredf16(F4, s_f);
  float T5 = bredf16(F5, s_f);
  int P0 = bredi16(I0, s_i);
  int P1 = bredi16(I1, s_i);
  int P2 = bredi16(I2, s_i);
  int P3 = bredi16(I3, s_i);

  if (tid == 0) {
    float N = (float)P1;
    float Nf = fmaxf(N, 1.f);
    out[0] = T0 / (Nf * 4.f);
    float wsum = N + (float)P2 * (1.f / 3.f);
    out[1] = (T1 + T5 * (1.f / 3.f)) / wsum;
    out[2] = (float)P0 / fmaxf(N, 1.f);
    out[3] = (float)P3 / fmaxf((float)P2, 1.f);
    out[4] = T2 / Nf;
    out[5] = T3 / Nf * 255.f;
    out[6] = T4 / Nf * 255.f;
    out[7] = N;
  }
}

extern "C" void kernel_launch(void* const* d_in, const int* in_sizes, int n_in,
                              void* d_out, int out_size, void* d_ws,
                              size_t ws_size, hipStream_t stream) {
  (void)n_in; (void)out_size; (void)ws_size;
  const float* loc = (const float*)d_in[0];
  const float* conf = (const float*)d_in[1];
  const float* gt = (const float*)d_in[2];
  const float* anchors = (const float*)d_in[3];
  int B = in_sizes[2] / 4;  // 64
  int A = in_sizes[3] / 4;  // 65536
  float* out = (float*)d_out;

  int spr = A / 4096;  // 16 k_main blocks (hist slices) per row

  char* w = (char*)d_ws;
  Accum* acc = (Accum*)w;
  size_t off = (sizeof(Accum) + 255) & ~(size_t)255;
  unsigned int* g1c = (unsigned int*)(w + off);
  off += (size_t)B * spr * NB * 4;
  off = (off + 255) & ~(size_t)255;
  unsigned int* keys = (unsigned int*)(w + off);

  dim3 gmain(spr, B);
  k_main<<<gmain, 256, 0, stream>>>(loc, conf, gt, anchors, acc, g1c, keys, A);
  k_select<<<B, 1024, 0, stream>>>(keys, g1c, acc, out, A, spr);
}

// Round 6
// 155.797 us; speedup vs baseline: 2.5601x; 1.1076x over previous
//
#include <hip/hip_runtime.h>
#include <math.h>

// MultiBoxLoss (SSD) on MI355X.
// R12: split R11's one-block-per-row k_select (52us, 25% CU, latency-bound)
// into a full-GPU fence-free scan + tiny finisher. Round-history isolation:
// R9/R10's 240-280us regressions came from device-scope same-address atomic
// chains in the append path (+ per-block acq_rel); R8/R11 (LDS counters, 64
// sync ops total) ran 44-52us. So:
// - k_scan grid(4,64)x1024: per-(row,chunk) ownership. Merge row hist + pick
//   (redundant, L2-hot); scan own 64KB chunk: above-bin -> register sums ->
//   plain stores; in-bin -> ballot append with LDS counter into the block's
//   PRIVATE global region cand[b][c] (no shared counter, no overflow: region
//   = chunk size). Zero device atomics, zero fences.
// - k_fin grid(64)x256: per row, 10+10-bit LDS radix over ~1-4K candidates
//   (L2-hot), tie-select, combine with scan partials; last row block (64
//   acq_rel total, proven cheap) reduces the final outputs.
// 3 dispatches; k_main unchanged (passed 5 rounds); tie semantics unchanged.

#define MAXB 64
#define NSLOT 1024  // = (A/4096) * B = 16 * 64
#define NB 2048     // first-level bins, key bits [30:20]
#define CHUNKS 4    // scan chunks per row

struct Accum {
  float f_loc[NSLOT], f_clsp[NSLOT], f_perr[NSLOT], f_se0[NSLOT], f_se1[NSLOT];
  int i_pcor[NSLOT], i_pcnt[NSLOT];
  float f_clsn_row[MAXB];
  unsigned int i_ntot_row[MAXB], i_ncor_row[MAXB];
  float sc_cls[MAXB][CHUNKS];
  int sc_ncnt[MAXB][CHUNKS], sc_ncor[MAXB][CHUNKS];
  unsigned int sc_ccnt[MAXB][CHUNKS];
  unsigned int tstar[MAXB], rrank[MAXB];
  unsigned int done;
};

__device__ __forceinline__ float iou_f(float4 g, float4 an) {
  float ax0 = an.x - an.z * 0.5f, ay0 = an.y - an.w * 0.5f;
  float ax1 = an.x + an.z * 0.5f, ay1 = an.y + an.w * 0.5f;
  float ltx = fmaxf(g.x, ax0), lty = fmaxf(g.y, ay0);
  float rbx = fminf(g.z, ax1), rby = fminf(g.w, ay1);
  float w = fmaxf(rbx - ltx, 0.f), h = fmaxf(rby - lty, 0.f);
  float inter = w * h;
  float area_g = (g.z - g.x) * (g.w - g.y);
  float area_a = (ax1 - ax0) * (ay1 - ay0);
  return inter / (area_g + area_a - inter);
}

__device__ __forceinline__ float sl1(float x) {
  float ax = fabsf(x);
  return ax < 1.f ? 0.5f * x * x : ax - 0.5f;
}

// keys + positive losses + fused 2048-bin count hist slices. grid (A/4096,B).
__global__ __launch_bounds__(256) void k_main(
    const float* __restrict__ loc_pred, const float* __restrict__ conf,
    const float* __restrict__ gt, const float* __restrict__ anchors,
    Accum* __restrict__ acc, unsigned int* __restrict__ g1c,
    unsigned int* __restrict__ keys, int A) {
  int b = blockIdx.y;
  int tid = threadIdx.x;
  int lane = tid & 63, wv = tid >> 6;
  __shared__ unsigned int hist[4][NB];  // wave-private replicas, 32 KB
  __shared__ float smf[5][4];
  __shared__ int smi[2][4];
  for (int i = tid; i < 4 * NB; i += 256) ((unsigned int*)hist)[i] = 0u;
  __syncthreads();

  float4 g4 = reinterpret_cast<const float4*>(gt)[b];
  const float4* conf4 = reinterpret_cast<const float4*>(conf);
  const float4* anc4 = reinterpret_cast<const float4*>(anchors);
  const float4* loc4 = reinterpret_cast<const float4*>(loc_pred);
  int abase = blockIdx.x * 4096;
  long long cbase = ((long long)b * A + abase) >> 1;  // float4 units
  uint2* keys2 = reinterpret_cast<uint2*>(keys);

  float loc_s = 0.f, clsp = 0.f, perr = 0.f, se0 = 0.f, se1 = 0.f;
  int pcnt = 0, pcor = 0;

#pragma unroll
  for (int j = 0; j < 8; ++j) {
    float4 cc = conf4[cbase + tid + j * 256];
    int a0 = abase + 2 * (tid + j * 256);
    uint2 kv;
#pragma unroll
    for (int h = 0; h < 2; ++h) {
      int a = a0 + h;
      float c0 = h ? cc.z : cc.x;
      float c1 = h ? cc.w : cc.y;
      float4 an = anc4[a];
      float ov = iou_f(g4, an);
      // softplus: logf(1+expf(-|d|)) bit-identical to two-expf form
      float s = logf(1.0f + expf(-fabsf(c1 - c0)));
      float m = fmaxf(c0, c1);
      unsigned int kk = 0u;
      if (ov <= 0.3f) kk = __float_as_uint((m - c0) + s);
      if (c1 > c0) kk |= 0x80000000u;
      if (h) kv.y = kk; else kv.x = kk;
      atomicAdd(&hist[wv][(kk & 0x7FFFFFFFu) >> 20], 1u);
      if (ov >= 0.6f) {
        float4 lp = loc4[(long long)b * A + a];
        float gcx = (g4.x + g4.z) * 0.5f, gcy = (g4.y + g4.w) * 0.5f;
        float gw = g4.z - g4.x, gh = g4.w - g4.y;
        float t0 = (gcx - an.x) / (0.1f * an.z);
        float t1 = (gcy - an.y) / (0.1f * an.w);
        float t2 = logf(gw / an.z) / 0.2f;
        float t3 = logf(gh / an.w) / 0.2f;
        loc_s += sl1(lp.x - t0) + sl1(lp.y - t1) + sl1(lp.z - t2) +
                 sl1(lp.w - t3);
        clsp += (m - c1) + s;
        pcnt += 1;
        pcor += (c1 > c0) ? 1 : 0;
        float dcx = an.x + lp.x * 0.1f * an.z;
        float dcy = an.y + lp.y * 0.1f * an.w;
        float dw = an.z * expf(lp.z * 0.2f);
        float dh = an.w * expf(lp.w * 0.2f);
        float dx0 = dcx - dw * 0.5f, dy0 = dcy - dh * 0.5f;
        float ex = (g4.x - dx0) * 255.f, ey = (g4.y - dy0) * 255.f;
        perr += sqrtf(ex * ex + ey * ey);
        se0 += fabsf(g4.z - (dx0 + dw));
        se1 += fabsf(g4.w - (dy0 + dh));
      }
    }
    keys2[cbase + tid + j * 256] = kv;
  }

  // wave-reduce positive stats
  float fv[5] = {loc_s, clsp, perr, se0, se1};
  int iv[2] = {pcnt, pcor};
#pragma unroll
  for (int q = 0; q < 5; ++q) {
    float v = fv[q];
#pragma unroll
    for (int o = 32; o > 0; o >>= 1) v += __shfl_down(v, o, 64);
    if (lane == 0) smf[q][wv] = v;
  }
#pragma unroll
  for (int q = 0; q < 2; ++q) {
    int v = iv[q];
#pragma unroll
    for (int o = 32; o > 0; o >>= 1) v += __shfl_down(v, o, 64);
    if (lane == 0) smi[q][wv] = v;
  }
  __syncthreads();

  // flush hist slice (non-atomic: per-(row,block) region, no init needed)
  {
    int slot = b * gridDim.x + blockIdx.x;
    unsigned int* dst = g1c + (long long)slot * NB;
    for (int i = tid; i < NB; i += 256)
      dst[i] = hist[0][i] + hist[1][i] + hist[2][i] + hist[3][i];
  }

  if (tid == 0) {
    float L = 0, C = 0, P = 0, S0 = 0, S1 = 0;
    int PC = 0, COR = 0;
    for (int w2 = 0; w2 < 4; ++w2) {
      L += smf[0][w2]; C += smf[1][w2]; P += smf[2][w2];
      S0 += smf[3][w2]; S1 += smf[4][w2];
      PC += smi[0][w2]; COR += smi[1][w2];
    }
    int slot = b * gridDim.x + blockIdx.x;
    acc->f_loc[slot] = L;
    acc->f_clsp[slot] = C;
    acc->f_perr[slot] = P;
    acc->f_se0[slot] = S0;
    acc->f_se1[slot] = S1;
    acc->i_pcor[slot] = COR;
    acc->i_pcnt[slot] = PC;
    if (slot == 0) acc->done = 0u;
  }
}

// pick over per-thread register counts, 1024-thr (16-wave) blocks.
// thread t owns bins [t*PER,(t+1)*PER). Returns (bin, residual rank).
template <int PER>
__device__ uint2 pickR(const unsigned int* cnt, int kr, unsigned int* s_wsum,
                       volatile unsigned int* s_bin,
                       volatile unsigned int* s_kr) {
  const int tid = threadIdx.x, lane = tid & 63, wv = tid >> 6;
  unsigned int my = 0;
#pragma unroll
  for (int i = 0; i < PER; ++i) my += cnt[i];
  unsigned int v = my;
#pragma unroll
  for (int o = 1; o < 64; o <<= 1) {
    unsigned int tv = __shfl_down(v, o, 64);
    if (lane + o < 64) v += tv;
  }
  if (lane == 0) s_wsum[wv] = v;
  __syncthreads();
  unsigned int off = 0;
#pragma unroll
  for (int w2 = 0; w2 < 16; ++w2)
    if (w2 > wv) off += s_wsum[w2];
  unsigned int incl = v + off;
  unsigned int above = incl - my;
  if ((int)above < kr && kr <= (int)incl) {
    int kk = kr - (int)above;
#pragma unroll
    for (int i = PER - 1; i >= 0; --i) {
      int c = (int)cnt[i];
      if (kk <= c) {
        *s_bin = (unsigned int)(tid * PER + i);
        *s_kr = (unsigned int)kk;
        break;
      }
      kk -= c;
    }
  }
  __syncthreads();
  uint2 r;
  r.x = *s_bin;
  r.y = *s_kr;
  __syncthreads();
  return r;
}

// same for 256-thr (4-wave) blocks
template <int PER>
__device__ uint2 pick4(const unsigned int* cnt, int kr, unsigned int* s_wsum,
                       volatile unsigned int* s_bin,
                       volatile unsigned int* s_kr) {
  const int tid = threadIdx.x, lane = tid & 63, wv = tid >> 6;
  unsigned int my = 0;
#pragma unroll
  for (int i = 0; i < PER; ++i) my += cnt[i];
  unsigned int v = my;
#pragma unroll
  for (int o = 1; o < 64; o <<= 1) {
    unsigned int tv = __shfl_down(v, o, 64);
    if (lane + o < 64) v += tv;
  }
  if (lane == 0) s_wsum[wv] = v;
  __syncthreads();
  unsigned int off = 0;
#pragma unroll
  for (int w2 = 0; w2 < 4; ++w2)
    if (w2 > wv) off += s_wsum[w2];
  unsigned int incl = v + off;
  unsigned int above = incl - my;
  if ((int)above < kr && kr <= (int)incl) {
    int kk = kr - (int)above;
#pragma unroll
    for (int i = PER - 1; i >= 0; --i) {
      int c = (int)cnt[i];
      if (kk <= c) {
        *s_bin = (unsigned int)(tid * PER + i);
        *s_kr = (unsigned int)kk;
        break;
      }
      kk -= c;
    }
  }
  __syncthreads();
  uint2 r;
  r.x = *s_bin;
  r.y = *s_kr;
  __syncthreads();
  return r;
}

__device__ __forceinline__ float bredf16(float v, float* s) {
#pragma unroll
  for (int o = 32; o > 0; o >>= 1) v += __shfl_down(v, o, 64);
  int lane = threadIdx.x & 63, wv = threadIdx.x >> 6;
  if (lane == 0) s[wv] = v;
  __syncthreads();
  float r = 0;
#pragma unroll
  for (int w = 0; w < 16; ++w) r += s[w];
  __syncthreads();
  return r;
}

__device__ __forceinline__ int bredi16(int v, int* s) {
#pragma unroll
  for (int o = 32; o > 0; o >>= 1) v += __shfl_down(v, o, 64);
  int lane = threadIdx.x & 63, wv = threadIdx.x >> 6;
  if (lane == 0) s[wv] = v;
  __syncthreads();
  int r = 0;
#pragma unroll
  for (int w = 0; w < 16; ++w) r += s[w];
  __syncthreads();
  return r;
}

__device__ __forceinline__ float bredf4(float v, float* s) {
#pragma unroll
  for (int o = 32; o > 0; o >>= 1) v += __shfl_down(v, o, 64);
  int lane = threadIdx.x & 63, wv = threadIdx.x >> 6;
  if (lane == 0) s[wv] = v;
  __syncthreads();
  float r = s[0] + s[1] + s[2] + s[3];
  __syncthreads();
  return r;
}

__device__ __forceinline__ int bredi4(int v, int* s) {
#pragma unroll
  for (int o = 32; o > 0; o >>= 1) v += __shfl_down(v, o, 64);
  int lane = threadIdx.x & 63, wv = threadIdx.x >> 6;
  if (lane == 0) s[wv] = v;
  __syncthreads();
  int r = s[0] + s[1] + s[2] + s[3];
  __syncthreads();
  return r;
}

// grid (CHUNKS, B) x 1024. Fence-free full-GPU scan: merge hist + pick; scan
// own chunk (above-bin: registers; in-bin: LDS-counter ballot append into the
// block's PRIVATE global region). Plain stores only.
__global__ __launch_bounds__(1024) void k_scan(
    const unsigned int* __restrict__ keys, const unsigned int* __restrict__ g1c,
    Accum* __restrict__ acc, unsigned int* __restrict__ cand, int A, int spr) {
  int b = blockIdx.y;
  int c = blockIdx.x;
  int tid = threadIdx.x;
  int lane = tid & 63;
  __shared__ unsigned int s_wsum[16];
  __shared__ volatile unsigned int s_bin, s_kr;
  __shared__ int s_np[16];
  __shared__ unsigned int s_ccnt;
  __shared__ float s_f[16];
  __shared__ int s_i[16];

  // merge the row's spr hist slices (2 bins/thread, uint2 loads)
  unsigned int cnt2[2] = {0u, 0u};
  {
    const uint2* pc =
        reinterpret_cast<const uint2*>(g1c + (long long)b * spr * NB);
    for (int s = 0; s < spr; ++s) {
      uint2 p = pc[s * (NB / 2) + tid];
      cnt2[0] += p.x;
      cnt2[1] += p.y;
    }
  }
  if (tid < spr) s_np[tid] = acc->i_pcnt[b * spr + tid];
  if (tid == 0) s_ccnt = 0u;
  __syncthreads();

  int np = 0;
  for (int i = 0; i < spr; ++i) np += s_np[i];
  int k = 3 * np;
  if (k < 10) k = 10;
  if (k > A - 1) k = A - 1;

  uint2 p1 = pickR<2>(cnt2, k, s_wsum, &s_bin, &s_kr);
  unsigned int tstar = p1.x;
  int r = (int)p1.y;
  if (c == 0 && tid == 0) {
    acc->tstar[b] = tstar;
    acc->rrank[b] = (unsigned int)r;
  }

  // scan own chunk (A/CHUNKS keys; 4 uint4 per thread)
  int ck = A / CHUNKS;
  const uint4* k4 = reinterpret_cast<const uint4*>(keys);
  long long base4 = (((long long)b * A) >> 2) + (long long)c * (ck >> 2);
  unsigned int* crow = cand + (long long)b * A + (long long)c * ck;
  float cls = 0.f;
  int ncnt = 0, ncor = 0;
  uint4 v[4];
#pragma unroll
  for (int j = 0; j < 4; ++j) v[j] = k4[base4 + tid + j * 1024];
#pragma unroll
  for (int j = 0; j < 4; ++j) {
    unsigned int ks[4] = {v[j].x, v[j].y, v[j].z, v[j].w};
#pragma unroll
    for (int e = 0; e < 4; ++e) {
      unsigned int key = ks[e];
      unsigned int k31 = key & 0x7FFFFFFFu;
      unsigned int vp = k31 >> 20;
      if (vp > tstar) {
        cls += __uint_as_float(k31);
        ncnt += 1;
        ncor += (int)((key >> 31) ^ 1u);
      }
      bool inb = (vp == tstar);
      unsigned long long mb = __ballot(inb);
      if (mb) {
        int leader = __ffsll((unsigned long long)mb) - 1;
        unsigned int base = 0;
        if (lane == leader)
          base = atomicAdd(&s_ccnt, (unsigned int)__popcll(mb));
        base = __shfl(base, leader, 64);
        if (inb) crow[base + __popcll(mb & ((1ull << lane) - 1ull))] = key;
      }
    }
  }

  float C = bredf16(cls, s_f);
  int NC = bredi16(ncnt, s_i);
  int CR = bredi16(ncor, s_i);
  if (tid == 0) {
    acc->sc_cls[b][c] = C;
    acc->sc_ncnt[b][c] = NC;
    acc->sc_ncor[b][c] = CR;
    acc->sc_ccnt[b][c] = s_ccnt;
  }
}

// grid (B) x 256. Per row: 10+10-bit LDS radix over the candidates (L2-hot),
// tie-select, combine with scan partials; last row block reduces outputs.
__global__ __launch_bounds__(256) void k_fin(
    const unsigned int* __restrict__ cand, Accum* __restrict__ acc,
    float* __restrict__ out, int A, int spr) {
  int b = blockIdx.x;
  int tid = threadIdx.x;
  __shared__ unsigned int hist2[1024];
  __shared__ unsigned int s_wsum[4];
  __shared__ volatile unsigned int s_bin, s_kr;
  __shared__ unsigned int s_eq, s_last;
  __shared__ float s_f[4];
  __shared__ int s_i[4];

  unsigned int tstar = acc->tstar[b];
  int r = (int)acc->rrank[b];
  int ck = A / CHUNKS;
  unsigned int cc[CHUNKS];
#pragma unroll
  for (int c = 0; c < CHUNKS; ++c) cc[c] = acc->sc_ccnt[b][c];
  const unsigned int* crow = cand + (long long)b * A;
  if (tid == 0) s_eq = 0u;

  // level 2: bits [19:10] (all candidates share bin tstar; no prefix check)
  for (int i = tid; i < 1024; i += 256) hist2[i] = 0u;
  __syncthreads();
#pragma unroll
  for (int c = 0; c < CHUNKS; ++c)
    for (unsigned int i = tid; i < cc[c]; i += 256)
      atomicAdd(&hist2[(crow[c * ck + i] >> 10) & 0x3FFu], 1u);
  __syncthreads();
  unsigned int cl[4];
#pragma unroll
  for (int i = 0; i < 4; ++i) cl[i] = hist2[tid * 4 + i];
  uint2 p2 = pick4<4>(cl, r, s_wsum, &s_bin, &s_kr);
  r = (int)p2.y;

  // level 3: bits [9:0]
  for (int i = tid; i < 1024; i += 256) hist2[i] = 0u;
  __syncthreads();
#pragma unroll
  for (int c = 0; c < CHUNKS; ++c)
    for (unsigned int i = tid; i < cc[c]; i += 256) {
      unsigned int k31 = crow[c * ck + i] & 0x7FFFFFFFu;
      if (((k31 >> 10) & 0x3FFu) == p2.x) atomicAdd(&hist2[k31 & 0x3FFu], 1u);
    }
  __syncthreads();
#pragma unroll
  for (int i = 0; i < 4; ++i) cl[i] = hist2[tid * 4 + i];
  uint2 p3 = pick4<4>(cl, r, s_wsum, &s_bin, &s_kr);
  unsigned int thr = (tstar << 20) | (p2.x << 10) | p3.x;
  int need = (int)p3.y;

  // selection among candidates
  float cls = 0.f;
  int ncnt = 0, ncor = 0;
#pragma unroll
  for (int c = 0; c < CHUNKS; ++c)
    for (unsigned int i = tid; i < cc[c]; i += 256) {
      unsigned int key = crow[c * ck + i];
      unsigned int k31 = key & 0x7FFFFFFFu;
      bool s = false;
      if (k31 > thr) {
        s = true;
      } else if (k31 == thr) {
        unsigned int ord = atomicAdd(&s_eq, 1u);
        if ((int)ord < need) s = true;
      }
      if (s) {
        cls += __uint_as_float(k31);
        ncnt += 1;
        ncor += (int)((key >> 31) ^ 1u);
      }
    }
  float C = bredf4(cls, s_f);
  int NC = bredi4(ncnt, s_i);
  int CR = bredi4(ncor, s_i);
  if (tid == 0) {
    float c0 = 0;
    int n0 = 0, r0 = 0;
    for (int c = 0; c < CHUNKS; ++c) {
      c0 += acc->sc_cls[b][c];
      n0 += acc->sc_ncnt[b][c];
      r0 += acc->sc_ncor[b][c];
    }
    acc->f_clsn_row[b] = C + c0;
    acc->i_ntot_row[b] = (unsigned int)(NC + n0);
    acc->i_ncor_row[b] = (unsigned int)(CR + r0);
  }

  // last-row-done final reduction (64 acq_rel total)
  __threadfence();
  if (tid == 0) {
    unsigned int old = __hip_atomic_fetch_add(&acc->done, 1u, __ATOMIC_ACQ_REL,
                                              __HIP_MEMORY_SCOPE_AGENT);
    s_last = (old == (unsigned int)(gridDim.x - 1)) ? 1u : 0u;
  }
  __syncthreads();
  if (!s_last) return;
  __threadfence();

  int B = (int)gridDim.x;
  int nslot = spr * B;
  float F0 = 0, F1 = 0, F2 = 0, F3 = 0, F4 = 0, F5 = 0;
  int I0 = 0, I1 = 0, I2 = 0, I3 = 0;
  for (int i = tid; i < nslot; i += 256) {
    F0 += acc->f_loc[i];
    F1 += acc->f_clsp[i];
    F2 += acc->f_perr[i];
    F3 += acc->f_se0[i];
    F4 += acc->f_se1[i];
    I0 += acc->i_pcor[i];
    I1 += acc->i_pcnt[i];
  }
  for (int i = tid; i < B; i += 256) {
    F5 += acc->f_clsn_row[i];
    I2 += (int)acc->i_ntot_row[i];
    I3 += (int)acc->i_ncor_row[i];
  }
  float T0 = bredf4(F0, s_f);
  float T1 = bredf4(F1, s_f);
  float T2 = bredf4(F2, s_f);
  float T3 = bredf4(F3, s_f);
  float T4 = bredf4(F4, s_f);
  float T5 = bredf4(F5, s_f);
  int P0 = bredi4(I0, s_i);
  int P1 = bredi4(I1, s_i);
  int P2 = bredi4(I2, s_i);
  int P3 = bredi4(I3, s_i);

  if (tid == 0) {
    float N = (float)P1;
    float Nf = fmaxf(N, 1.f);
    out[0] = T0 / (Nf * 4.f);
    float wsum = N + (float)P2 * (1.f / 3.f);
    out[1] = (T1 + T5 * (1.f / 3.f)) / wsum;
    out[2] = (float)P0 / fmaxf(N, 1.f);
    out[3] = (float)P3 / fmaxf((float)P2, 1.f);
    out[4] = T2 / Nf;
    out[5] = T3 / Nf * 255.f;
    out[6] = T4 / Nf * 255.f;
    out[7] = N;
  }
}

extern "C" void kernel_launch(void* const* d_in, const int* in_sizes, int n_in,
                              void* d_out, int out_size, void* d_ws,
                              size_t ws_size, hipStream_t stream) {
  (void)n_in; (void)out_size; (void)ws_size;
  const float* loc = (const float*)d_in[0];
  const float* conf = (const float*)d_in[1];
  const float* gt = (const float*)d_in[2];
  const float* anchors = (const float*)d_in[3];
  int B = in_sizes[2] / 4;  // 64
  int A = in_sizes[3] / 4;  // 65536
  float* out = (float*)d_out;

  int spr = A / 4096;  // 16 k_main blocks (hist slices) per row

  char* w = (char*)d_ws;
  Accum* acc = (Accum*)w;
  size_t off = (sizeof(Accum) + 255) & ~(size_t)255;
  unsigned int* g1c = (unsigned int*)(w + off);
  off += (size_t)B * spr * NB * 4;
  off = (off + 255) & ~(size_t)255;
  unsigned int* keys = (unsigned int*)(w + off);
  off += (size_t)B * A * 4;
  unsigned int* cand = (unsigned int*)(w + off);

  dim3 gmain(spr, B);
  k_main<<<gmain, 256, 0, stream>>>(loc, conf, gt, anchors, acc, g1c, keys, A);
  dim3 gscan(CHUNKS, B);
  k_scan<<<gscan, 1024, 0, stream>>>(keys, g1c, acc, cand, A, spr);
  k_fin<<<B, 256, 0, stream>>>(cand, acc, out, A, spr);
}